// Round 1
// baseline (266.728 us; speedup 1.0000x reference)
//
#include <hip/hip_runtime.h>
#include <math.h>

namespace {

constexpr int B = 4, C = 64, O = 64, H = 128, W = 128;
constexpr int K2 = 9;
constexpr int HW = H * W;
constexpr int NPIX = B * HW;          // 65536
constexpr int OC27 = 27;              // 18 offset + 9 mod channels

__global__ __launch_bounds__(256, 1)
void dcn_fused(const float* __restrict__ x,
               const float* __restrict__ weight,
               const float* __restrict__ bias,
               const float* __restrict__ ow,
               const float* __restrict__ ob,
               const float* __restrict__ mw,
               const float* __restrict__ mb,
               float* __restrict__ out)
{
    // Reused LDS: phase 1 = owt[(k*C+c)*27+oc] (62 KB), phase 2 = wt[(k*C+c)*64+o] (147 KB)
    __shared__ float lds[K2 * C * O];   // 36864 floats = 147456 B

    const int tid = threadIdx.x;
    const int p   = blockIdx.x * 256 + tid;
    const int b   = p >> 14;            // / 16384
    const int hw  = p & (HW - 1);
    const int ho  = hw >> 7;
    const int wo  = hw & (W - 1);

    // ---- stage offset+mod weights transposed (coalesced global reads) ----
    for (int lin = tid; lin < 18 * C * K2; lin += 256) {
        const int oc = lin / (C * K2);
        const int r  = lin - oc * (C * K2);
        const int c  = r / K2;
        const int k  = r - c * K2;
        lds[(k * C + c) * OC27 + oc] = ow[lin];
    }
    for (int lin = tid; lin < 9 * C * K2; lin += 256) {
        const int oc = lin / (C * K2);
        const int r  = lin - oc * (C * K2);
        const int c  = r / K2;
        const int k  = r - c * K2;
        lds[(k * C + c) * OC27 + 18 + oc] = mw[lin];
    }
    __syncthreads();

    const float* __restrict__ xb = x + b * C * HW;

    // ---- phase 1: 27-channel 3x3 conv (18 offsets, 9 mod) ----
    float acc[OC27];
    #pragma unroll
    for (int i = 0; i < 18; ++i) acc[i] = ob[i];
    #pragma unroll
    for (int i = 0; i < 9; ++i)  acc[18 + i] = mb[i];

    #pragma unroll
    for (int k = 0; k < K2; ++k) {
        const int ky = k / 3, kx = k % 3;
        const int y  = ho - 1 + ky;
        const int xx = wo - 1 + kx;
        const bool valid = (y >= 0) & (y < H) & (xx >= 0) & (xx < W);
        const float vf = valid ? 1.0f : 0.0f;
        const int  lin = valid ? (y * W + xx) : 0;
        const float* __restrict__ xp = xb + lin;
        const float* __restrict__ wl = &lds[k * C * OC27];
        for (int c = 0; c < C; ++c) {
            const float xv = vf * xp[c * HW];
            #pragma unroll
            for (int oc = 0; oc < OC27; ++oc)
                acc[oc] = fmaf(xv, wl[c * OC27 + oc], acc[oc]);
        }
    }

    // ---- positions + modulation mean ----
    float syk[K2], sxk[K2];
    float mm = 0.0f;
    #pragma unroll
    for (int k = 0; k < K2; ++k) {
        syk[k] = (float)ho + acc[k];
        sxk[k] = (float)wo + acc[9 + k];
        mm += 1.0f / (1.0f + __expf(-acc[18 + k]));
    }
    mm *= (1.0f / 9.0f);

    // ---- stage main weights transposed: lds[(k*C+c)*O + o] ----
    __syncthreads();
    for (int lin = tid; lin < O * C * K2; lin += 256) {
        const int o = lin / (C * K2);
        const int r = lin - o * (C * K2);
        const int c = r / K2;
        const int k = r - c * K2;
        lds[(k * C + c) * O + o] = weight[lin];
    }
    __syncthreads();

    // ---- phase 2: bilinear sample + einsum ----
    float acc2[O];
    #pragma unroll
    for (int o = 0; o < O; ++o) acc2[o] = 0.0f;

    #pragma unroll
    for (int k = 0; k < K2; ++k) {
        const float fy  = floorf(syk[k]);
        const float fx  = floorf(sxk[k]);
        const float wy1 = syk[k] - fy;
        const float wx1 = sxk[k] - fx;
        const float wy0 = 1.0f - wy1;
        const float wx0 = 1.0f - wx1;
        const int y0 = (int)fy, x0 = (int)fx;
        const int y1 = y0 + 1,  x1 = x0 + 1;
        const float vy0 = (y0 >= 0 && y0 < H) ? 1.0f : 0.0f;
        const float vy1 = (y1 >= 0 && y1 < H) ? 1.0f : 0.0f;
        const float vx0 = (x0 >= 0 && x0 < W) ? 1.0f : 0.0f;
        const float vx1 = (x1 >= 0 && x1 < W) ? 1.0f : 0.0f;
        const int cy0 = min(max(y0, 0), H - 1);
        const int cy1 = min(max(y1, 0), H - 1);
        const int cx0 = min(max(x0, 0), W - 1);
        const int cx1 = min(max(x1, 0), W - 1);
        const int l00 = cy0 * W + cx0;
        const int l01 = cy0 * W + cx1;
        const int l10 = cy1 * W + cx0;
        const int l11 = cy1 * W + cx1;
        // fold corner validity (zero padding) into bilinear weights
        const float w00 = wy0 * wx0 * vy0 * vx0;
        const float w01 = wy0 * wx1 * vy0 * vx1;
        const float w10 = wy1 * wx0 * vy1 * vx0;
        const float w11 = wy1 * wx1 * vy1 * vx1;
        const float* __restrict__ wl = &lds[k * C * O];
        for (int c = 0; c < C; ++c) {
            const float* __restrict__ xc = xb + c * HW;
            const float s = w00 * xc[l00] + w01 * xc[l01]
                          + w10 * xc[l10] + w11 * xc[l11];
            #pragma unroll
            for (int o = 0; o < O; ++o)
                acc2[o] = fmaf(s, wl[c * O + o], acc2[o]);
        }
    }

    // ---- epilogue: modulate + bias, coalesced per-o stores ----
    float* __restrict__ op = out + b * O * HW + hw;
    #pragma unroll
    for (int o = 0; o < O; ++o)
        op[o * HW] = acc2[o] * mm + bias[o];
}

} // namespace

extern "C" void kernel_launch(void* const* d_in, const int* in_sizes, int n_in,
                              void* d_out, int out_size, void* d_ws, size_t ws_size,
                              hipStream_t stream)
{
    const float* x  = (const float*)d_in[0];
    const float* w  = (const float*)d_in[1];
    const float* bs = (const float*)d_in[2];
    const float* ow = (const float*)d_in[3];
    const float* ob = (const float*)d_in[4];
    const float* mw = (const float*)d_in[5];
    const float* mb = (const float*)d_in[6];
    float* out = (float*)d_out;

    dim3 grid(NPIX / 256), block(256);
    hipLaunchKernelGGL(dcn_fused, grid, block, 0, stream,
                       x, w, bs, ow, ob, mw, mb, out);
}

// Round 2
// 177.184 us; speedup vs baseline: 1.5054x; 1.5054x over previous
//
#include <hip/hip_runtime.h>
#include <math.h>

namespace {

constexpr int B = 4, C = 64, O = 64, H = 128, W = 128;
constexpr int K2 = 9;
constexpr int HW = H * W;
constexpr int PIX = 128;              // pixels per block = one image row

typedef __attribute__((ext_vector_type(8))) short short8v;
typedef __attribute__((ext_vector_type(4))) float f32x4;

__device__ inline unsigned short f2bf(float f) {
    unsigned u = __float_as_uint(f);
    return (unsigned short)((u + 0x7FFFu + ((u >> 16) & 1u)) >> 16);
}

// swizzled byte offset within the sT tile: row p (128 B/row), byte off in [0,128)
__device__ inline int swz(int p, int off) {
    return (p << 7) + (off ^ ((p & 7) << 4));
}

__global__ __launch_bounds__(256, 2)
void dcn_mfma(const float* __restrict__ x,
              const float* __restrict__ weight,
              const float* __restrict__ bias,
              const float* __restrict__ ow,
              const float* __restrict__ ob,
              const float* __restrict__ mw,
              const float* __restrict__ mb,
              float* __restrict__ out)
{
    __shared__ __align__(16) unsigned char sT[PIX * 128]; // bf16 [p][c] tile, swizzled, 16KB
    __shared__ float offL[32 * PIX];                      // offset-conv out [ch][p], 16KB
    __shared__ float mmL[PIX];

    const int tid  = threadIdx.x;
    const int lane = tid & 63;
    const int wv   = tid >> 6;

    // XCD-aware bijective swizzle (512 % 8 == 0)
    const int bid = (blockIdx.x & 7) * 64 + (blockIdx.x >> 3);
    const int b   = bid >> 7;
    const int ho  = bid & 127;
    const float* __restrict__ xb = x + (size_t)b * C * HW;

    const int p    = tid & 127;   // this thread's pixel (wo)
    const int half = tid >> 7;    // c-range selector for staging
    const int wo   = p;

    const int lrow = lane & 15;   // fragment row/col selector
    const int lk   = lane >> 4;   // k-group selector

    // ================= Phase A: offset/mod conv via MFMA =================
    f32x4 oacc[2][2]; // [mt][nt]; wave covers p-cols [wv*32, wv*32+32)
    #pragma unroll
    for (int mt = 0; mt < 2; ++mt)
        #pragma unroll
        for (int nt = 0; nt < 2; ++nt)
            #pragma unroll
            for (int j = 0; j < 4; ++j) oacc[mt][nt][j] = 0.0f;

    #pragma unroll
    for (int k = 0; k < K2; ++k) {
        const int ky = k / 3, kx = k % 3;

        // --- A-fragments for this tap: ow/mw rows (27 used, pad to 32) ---
        short8v afrA[2][2]; // [ks][mt]
        #pragma unroll
        for (int ks = 0; ks < 2; ++ks) {
            #pragma unroll
            for (int mt = 0; mt < 2; ++mt) {
                const int r  = mt * 16 + lrow;
                const int cb = ks * 32 + lk * 8;
                #pragma unroll
                for (int j = 0; j < 8; ++j) {
                    float wvv = 0.0f;
                    if (r < 18)      wvv = ow[((size_t)(r * C + cb + j)) * 9 + k];
                    else if (r < 27) wvv = mw[((size_t)((r - 18) * C + cb + j)) * 9 + k];
                    afrA[ks][mt][j] = (short)f2bf(wvv);
                }
            }
        }

        // --- stage shifted patch: sT[p][c] = x[b][c][ho-1+ky][wo-1+kx] ---
        {
            const int y  = ho - 1 + ky;
            const int xx = wo - 1 + kx;
            const bool v = (y >= 0) & (y < H) & (xx >= 0) & (xx < W);
            const float vf = v ? 1.0f : 0.0f;
            const float* __restrict__ xp = xb + (v ? (y * W + xx) : 0);
            #pragma unroll
            for (int q = 0; q < 4; ++q) {
                unsigned pk[4];
                #pragma unroll
                for (int e = 0; e < 4; ++e) {
                    const int c0 = half * 32 + q * 8 + e * 2;
                    const float s0 = vf * xp[(size_t)c0 * HW];
                    const float s1 = vf * xp[(size_t)(c0 + 1) * HW];
                    pk[e] = (unsigned)f2bf(s0) | ((unsigned)f2bf(s1) << 16);
                }
                uint4* dst = (uint4*)(sT + swz(p, half * 64 + q * 16));
                *dst = make_uint4(pk[0], pk[1], pk[2], pk[3]);
            }
        }
        __syncthreads();

        // --- MFMA accumulate ---
        #pragma unroll
        for (int ks = 0; ks < 2; ++ks) {
            #pragma unroll
            for (int nt = 0; nt < 2; ++nt) {
                const int pc = wv * 32 + nt * 16 + lrow;
                short8v bfr = *(const short8v*)(sT + swz(pc, ks * 64 + lk * 16));
                #pragma unroll
                for (int mt = 0; mt < 2; ++mt)
                    oacc[mt][nt] = __builtin_amdgcn_mfma_f32_16x16x32_bf16(
                        afrA[ks][mt], bfr, oacc[mt][nt], 0, 0, 0);
            }
        }
        __syncthreads();
    }

    // --- write offset-conv result (+bias) to LDS [ch][p] ---
    #pragma unroll
    for (int mt = 0; mt < 2; ++mt) {
        #pragma unroll
        for (int nt = 0; nt < 2; ++nt) {
            #pragma unroll
            for (int j = 0; j < 4; ++j) {
                const int r  = mt * 16 + lk * 4 + j;
                const int pc = wv * 32 + nt * 16 + lrow;
                float bv = 0.0f;
                if (r < 18)      bv = ob[r];
                else if (r < 27) bv = mb[r - 18];
                offL[r * PIX + pc] = oacc[mt][nt][j] + bv;
            }
        }
    }
    __syncthreads();

    // --- per-thread sampling positions + modulation mean ---
    float sy[K2], sx[K2];
    #pragma unroll
    for (int k = 0; k < K2; ++k) {
        sy[k] = (float)ho + offL[k * PIX + p];
        sx[k] = (float)wo + offL[(9 + k) * PIX + p];
    }
    if (half == 0) {
        float mm = 0.0f;
        #pragma unroll
        for (int k = 0; k < K2; ++k)
            mm += 1.0f / (1.0f + __expf(-offL[(18 + k) * PIX + p]));
        mmL[p] = mm * (1.0f / 9.0f);
    }

    // ================= Phase B: bilinear sample + main einsum =================
    f32x4 acc[8]; // N-tiles; wave owns o-tile [wv*16, wv*16+16)
    #pragma unroll
    for (int nt = 0; nt < 8; ++nt)
        #pragma unroll
        for (int j = 0; j < 4; ++j) acc[nt][j] = 0.0f;

    #pragma unroll
    for (int k = 0; k < K2; ++k) {
        // --- W fragments for this tap (from global, L2-hot) ---
        short8v afr[2]; // [ks]
        #pragma unroll
        for (int ks = 0; ks < 2; ++ks) {
            const int o  = wv * 16 + lrow;
            const int cb = ks * 32 + lk * 8;
            #pragma unroll
            for (int j = 0; j < 8; ++j)
                afr[ks][j] = (short)f2bf(weight[((size_t)(o * C + cb + j)) * 9 + k]);
        }

        // --- bilinear sample into sT[p][c] ---
        {
            const float fy  = floorf(sy[k]);
            const float fx  = floorf(sx[k]);
            const float wy1 = sy[k] - fy;
            const float wx1 = sx[k] - fx;
            const float wy0 = 1.0f - wy1;
            const float wx0 = 1.0f - wx1;
            const int y0 = (int)fy, x0 = (int)fx;
            const int y1 = y0 + 1,  x1 = x0 + 1;
            const float vy0 = (y0 >= 0 && y0 < H) ? 1.0f : 0.0f;
            const float vy1 = (y1 >= 0 && y1 < H) ? 1.0f : 0.0f;
            const float vx0 = (x0 >= 0 && x0 < W) ? 1.0f : 0.0f;
            const float vx1 = (x1 >= 0 && x1 < W) ? 1.0f : 0.0f;
            const int cy0 = min(max(y0, 0), H - 1);
            const int cy1 = min(max(y1, 0), H - 1);
            const int cx0 = min(max(x0, 0), W - 1);
            const int cx1 = min(max(x1, 0), W - 1);
            const int l00 = cy0 * W + cx0;
            const int l01 = cy0 * W + cx1;
            const int l10 = cy1 * W + cx0;
            const int l11 = cy1 * W + cx1;
            const float w00 = wy0 * wx0 * vy0 * vx0;
            const float w01 = wy0 * wx1 * vy0 * vx1;
            const float w10 = wy1 * wx0 * vy1 * vx0;
            const float w11 = wy1 * wx1 * vy1 * vx1;
            #pragma unroll
            for (int q = 0; q < 4; ++q) {
                unsigned pk[4];
                #pragma unroll
                for (int e = 0; e < 4; ++e) {
                    const int c0 = half * 32 + q * 8 + e * 2;
                    const float* __restrict__ xc0 = xb + (size_t)c0 * HW;
                    const float* __restrict__ xc1 = xc0 + HW;
                    const float s0 = w00 * xc0[l00] + w01 * xc0[l01]
                                   + w10 * xc0[l10] + w11 * xc0[l11];
                    const float s1 = w00 * xc1[l00] + w01 * xc1[l01]
                                   + w10 * xc1[l10] + w11 * xc1[l11];
                    pk[e] = (unsigned)f2bf(s0) | ((unsigned)f2bf(s1) << 16);
                }
                uint4* dst = (uint4*)(sT + swz(p, half * 64 + q * 16));
                *dst = make_uint4(pk[0], pk[1], pk[2], pk[3]);
            }
        }
        __syncthreads();

        // --- MFMA: out-tile += W_k · S_k ---
        #pragma unroll
        for (int ks = 0; ks < 2; ++ks) {
            #pragma unroll
            for (int nt = 0; nt < 8; ++nt) {
                const int pc = nt * 16 + lrow;
                short8v bfr = *(const short8v*)(sT + swz(pc, ks * 64 + lk * 16));
                acc[nt] = __builtin_amdgcn_mfma_f32_16x16x32_bf16(
                    afr[ks], bfr, acc[nt], 0, 0, 0);
            }
        }
        __syncthreads();
    }

    // ================= Epilogue: modulate + bias =================
    float bv[4];
    #pragma unroll
    for (int j = 0; j < 4; ++j)
        bv[j] = bias[wv * 16 + lk * 4 + j];

    #pragma unroll
    for (int nt = 0; nt < 8; ++nt) {
        const int pc  = nt * 16 + lrow;
        const float mmv = mmL[pc];
        #pragma unroll
        for (int j = 0; j < 4; ++j) {
            const int o = wv * 16 + lk * 4 + j;
            out[((size_t)(b * O + o)) * HW + ho * W + pc] = acc[nt][j] * mmv + bv[j];
        }
    }
}

} // namespace

extern "C" void kernel_launch(void* const* d_in, const int* in_sizes, int n_in,
                              void* d_out, int out_size, void* d_ws, size_t ws_size,
                              hipStream_t stream)
{
    const float* x  = (const float*)d_in[0];
    const float* w  = (const float*)d_in[1];
    const float* bs = (const float*)d_in[2];
    const float* ow = (const float*)d_in[3];
    const float* ob = (const float*)d_in[4];
    const float* mw = (const float*)d_in[5];
    const float* mb = (const float*)d_in[6];
    float* out = (float*)d_out;

    dim3 grid(B * H), block(256);   // 512 blocks, one image row each
    hipLaunchKernelGGL(dcn_mfma, grid, block, 0, stream,
                       x, w, bs, ow, ob, mw, mb, out);
}

// Round 5
// 85.190 us; speedup vs baseline: 3.1310x; 2.0799x over previous
//
#include <hip/hip_runtime.h>
#include <math.h>

namespace {

constexpr int B = 4, C = 64, O = 64, H = 128, W = 128, K2 = 9;
constexpr int HW = H * W;
constexpr int PIX = 128;   // fallback tile

typedef __attribute__((ext_vector_type(8))) short short8v;
typedef __attribute__((ext_vector_type(4))) float f32x4;

// 8-byte pair with 4-byte alignment
struct __attribute__((aligned(4))) fpair { float a, b; };

__device__ __forceinline__ unsigned f2bf(float f) {
    unsigned u = __float_as_uint(f);
    return (u + 0x7FFFu + ((u >> 16) & 1u)) >> 16;
}
__device__ __forceinline__ int swz(int p, int off) {
    return (p << 7) + (off ^ ((p & 7) << 4));
}

// workspace: packed weight fragments only
constexpr size_t WSW_OFF = 0;        // 4608 * 16 B  (main conv W-frags)
constexpr size_t WSA_OFF = 73728;    // 2304 * 16 B  (offset/mod conv A-frags)
constexpr size_t WS_NEED = 110592;

// ================= K0: pack weights into bf16 MFMA-fragment layout =================
__global__ void k0_pack(const float* __restrict__ w, const float* __restrict__ ow,
                        const float* __restrict__ mw, unsigned char* __restrict__ ws)
{
    const int id = blockIdx.x * 256 + threadIdx.x;
    if (id < 4608) {
        // wsW[k][ks][wv][lane]: o = wv*16+(lane&15), cb = ks*32+(lane>>4)*8
        const int k = id >> 9, rem = id & 511, ks = rem >> 8, r2 = rem & 255;
        const int wv = r2 >> 6, lane = r2 & 63;
        const int o = wv * 16 + (lane & 15), cb = ks * 32 + (lane >> 4) * 8;
        unsigned pk[4];
        #pragma unroll
        for (int e = 0; e < 4; ++e)
            pk[e] = f2bf(w[(o * C + cb + 2 * e) * 9 + k])
                  | (f2bf(w[(o * C + cb + 2 * e + 1) * 9 + k]) << 16);
        *(uint4*)(ws + WSW_OFF + (size_t)id * 16) = make_uint4(pk[0], pk[1], pk[2], pk[3]);
    } else if (id < 6912) {
        // wsA[k][ks][mt][lane]: r = mt*16+(lane&15) (27 rows used, pad 32)
        const int id2 = id - 4608;
        const int k = id2 >> 8, rem = id2 & 255, ks = rem >> 7, r2 = rem & 127;
        const int mt = r2 >> 6, lane = r2 & 63;
        const int r = mt * 16 + (lane & 15), cb = ks * 32 + (lane >> 4) * 8;
        unsigned pk[4];
        #pragma unroll
        for (int e = 0; e < 4; ++e) {
            float v0 = 0.f, v1 = 0.f;
            const int c0 = cb + 2 * e;
            if (r < 18)      { v0 = ow[(r * C + c0) * 9 + k];        v1 = ow[(r * C + c0 + 1) * 9 + k]; }
            else if (r < 27) { v0 = mw[((r - 18) * C + c0) * 9 + k]; v1 = mw[((r - 18) * C + c0 + 1) * 9 + k]; }
            pk[e] = f2bf(v0) | (f2bf(v1) << 16);
        }
        *(uint4*)(ws + WSA_OFF + (size_t)id2 * 16) = make_uint4(pk[0], pk[1], pk[2], pk[3]);
    }
}

// ====== fused kernel: 64-px strip, SINGLE-buffered sT, 2 barriers per tap ======
__global__ __launch_bounds__(256, 4)
void dcn_fused3(const float* __restrict__ x, const float* __restrict__ bias,
                const float* __restrict__ ob, const float* __restrict__ mb,
                const unsigned char* __restrict__ ws, float* __restrict__ out)
{
    __shared__ __align__(16) unsigned char sT[64 * 128]; // bf16 [p][c], swizzled (8 KB)
    __shared__ float offL[27 * 64];                      // sy/sx/mod-logit
    __shared__ float mmL[64];

    const int tid = threadIdx.x;
    const int lane = tid & 63, wv = tid >> 6;
    const int lrow = lane & 15, lk = lane >> 4;
    const int p = lane, grp = wv;

    const int raw = blockIdx.x;
    const int bid = (raw & 7) * 128 + (raw >> 3);   // XCD-contiguous, bijective (1024%8==0)
    const int b = bid >> 8, rr = bid & 255;
    const int ho = rr >> 1, p0 = (rr & 1) << 6;
    const int wo = p0 + p;

    const float* __restrict__ xb = x + b * C * HW;

    // ---------------- phase A: offset/mod conv ----------------
    f32x4 oacc[2];
    #pragma unroll
    for (int mt = 0; mt < 2; ++mt)
        #pragma unroll
        for (int j = 0; j < 4; ++j) oacc[mt][j] = 0.f;

    #pragma unroll
    for (int k = 0; k < 9; ++k) {
        // stage shifted patch: sT[p][c] = x[b][c][ho-1+ky][wo-1+kx]
        {
            const int ky = k / 3, kx = k - ky * 3;
            const int y = ho - 1 + ky, xx = wo - 1 + kx;
            const bool v = (y >= 0) & (y < H) & (xx >= 0) & (xx < W);
            const float vf = v ? 1.f : 0.f;
            const float* __restrict__ xp = xb + (v ? (y * W + xx) : 0);
            #pragma unroll
            for (int u = 0; u < 2; ++u) {
                unsigned pk[4];
                #pragma unroll
                for (int e = 0; e < 4; ++e) {
                    const int c0 = grp * 16 + u * 8 + 2 * e;
                    pk[e] = f2bf(vf * xp[c0 * HW]) | (f2bf(vf * xp[(c0 + 1) * HW]) << 16);
                }
                *(uint4*)(sT + swz(p, grp * 32 + u * 16)) = make_uint4(pk[0], pk[1], pk[2], pk[3]);
            }
        }
        __syncthreads();
        #pragma unroll
        for (int ks = 0; ks < 2; ++ks) {
            short8v bf = *(const short8v*)(sT + swz(wv * 16 + lrow, ks * 64 + lk * 16));
            #pragma unroll
            for (int mt = 0; mt < 2; ++mt) {
                short8v af = *(const short8v*)(ws + WSA_OFF +
                    (size_t)((((k * 2 + ks) * 2 + mt) * 64 + lane)) * 16);
                oacc[mt] = __builtin_amdgcn_mfma_f32_16x16x32_bf16(af, bf, oacc[mt], 0, 0, 0);
            }
        }
        __syncthreads();
    }

    // ---------------- positions into LDS ----------------
    {
        const int pc = wv * 16 + lrow;
        #pragma unroll
        for (int mt = 0; mt < 2; ++mt) {
            #pragma unroll
            for (int j = 0; j < 4; ++j) {
                const int r = mt * 16 + lk * 4 + j;
                const float val = oacc[mt][j];
                if (r < 9)       offL[r * 64 + pc] = (float)ho + ob[r] + val;        // sy
                else if (r < 18) offL[r * 64 + pc] = (float)(p0 + pc) + ob[r] + val; // sx
                else if (r < 27) offL[r * 64 + pc] = val + mb[r - 18];               // mod logit
            }
        }
    }
    __syncthreads();

    // positions to registers (static indices via unroll), mod-mean
    float sy[9], sx[9];
    #pragma unroll
    for (int k = 0; k < 9; ++k) {
        sy[k] = offL[k * 64 + p];
        sx[k] = offL[(9 + k) * 64 + p];
    }
    if (tid < 64) {
        float s = 0.f;
        #pragma unroll
        for (int i = 0; i < 9; ++i) s += 1.f / (1.f + __expf(-offL[(18 + i) * 64 + tid]));
        mmL[tid] = s * (1.f / 9.f);
    }

    // ---------------- phase B: bilinear sample + main einsum ----------------
    f32x4 acc[4];
    #pragma unroll
    for (int nt = 0; nt < 4; ++nt)
        #pragma unroll
        for (int j = 0; j < 4; ++j) acc[nt][j] = 0.f;

    #pragma unroll
    for (int k = 0; k < 9; ++k) {
        // bilinear sample into sT[p][c] (paired-x gather)
        {
            const float fy = floorf(sy[k]), fx = floorf(sx[k]);
            const float wy1 = sy[k] - fy, wx1 = sx[k] - fx;
            const float wy0 = 1.f - wy1, wx0 = 1.f - wx1;
            const int y0 = (int)fy, x0 = (int)fx;
            const float vy0 = (y0 >= 0 && y0 < H) ? 1.f : 0.f;
            const float vy1 = (y0 + 1 >= 0 && y0 + 1 < H) ? 1.f : 0.f;
            const float vx0 = (x0 >= 0 && x0 < W) ? 1.f : 0.f;
            const float vx1 = (x0 + 1 >= 0 && x0 + 1 < W) ? 1.f : 0.f;
            const int ry0 = min(max(y0, 0), H - 1), ry1 = min(max(y0 + 1, 0), H - 1);
            const int lx = min(max(x0, 0), W - 2);
            const bool eq = (x0 == lx);
            const float u00 = wy0 * vy0 * wx0 * vx0, u01 = wy0 * vy0 * wx1 * vx1;
            const float u10 = wy1 * vy1 * wx0 * vx0, u11 = wy1 * vy1 * wx1 * vx1;
            const float a0 = eq ? u00 : u01, b0 = eq ? u01 : u00;
            const float a1 = eq ? u10 : u11, b1 = eq ? u11 : u10;
            const float* __restrict__ base0 = xb + ry0 * W + lx;
            const float* __restrict__ base1 = xb + ry1 * W + lx;
            #pragma unroll
            for (int u = 0; u < 2; ++u) {
                unsigned pk[4];
                #pragma unroll
                for (int e = 0; e < 4; ++e) {
                    const int c0 = grp * 16 + u * 8 + 2 * e;
                    fpair q0 = *(const fpair*)(base0 + c0 * HW);
                    fpair q1 = *(const fpair*)(base1 + c0 * HW);
                    fpair q2 = *(const fpair*)(base0 + (c0 + 1) * HW);
                    fpair q3 = *(const fpair*)(base1 + (c0 + 1) * HW);
                    const float s0 = a0 * q0.a + b0 * q0.b + a1 * q1.a + b1 * q1.b;
                    const float s1 = a0 * q2.a + b0 * q2.b + a1 * q3.a + b1 * q3.b;
                    pk[e] = f2bf(s0) | (f2bf(s1) << 16);
                }
                *(uint4*)(sT + swz(p, grp * 32 + u * 16)) = make_uint4(pk[0], pk[1], pk[2], pk[3]);
            }
        }
        __syncthreads();
        #pragma unroll
        for (int ks = 0; ks < 2; ++ks) {
            short8v af = *(const short8v*)(ws + WSW_OFF +
                (size_t)(((k * 8 + ks * 4 + wv) * 64 + lane)) * 16);
            #pragma unroll
            for (int nt = 0; nt < 4; ++nt) {
                short8v bf = *(const short8v*)(sT + swz(nt * 16 + lrow, ks * 64 + lk * 16));
                acc[nt] = __builtin_amdgcn_mfma_f32_16x16x32_bf16(af, bf, acc[nt], 0, 0, 0);
            }
        }
        __syncthreads();
    }

    // ---------------- epilogue ----------------
    float bj[4];
    #pragma unroll
    for (int j = 0; j < 4; ++j) bj[j] = bias[wv * 16 + lk * 4 + j];
    #pragma unroll
    for (int nt = 0; nt < 4; ++nt) {
        const int pc = nt * 16 + lrow;
        const float mmv = mmL[pc];
        #pragma unroll
        for (int j = 0; j < 4; ++j) {
            const int o = wv * 16 + lk * 4 + j;
            out[(b * O + o) * HW + ho * W + p0 + pc] = acc[nt][j] * mmv + bj[j];
        }
    }
}

// ================= fallback (round-2 kernel, used if ws too small) =================
__global__ __launch_bounds__(256, 2)
void dcn_fallback(const float* __restrict__ x, const float* __restrict__ weight,
                  const float* __restrict__ bias, const float* __restrict__ ow,
                  const float* __restrict__ ob, const float* __restrict__ mw,
                  const float* __restrict__ mb, float* __restrict__ out)
{
    __shared__ __align__(16) unsigned char sT[PIX * 128];
    __shared__ float offL[32 * PIX];
    __shared__ float mmL[PIX];

    const int tid = threadIdx.x;
    const int lane = tid & 63;
    const int wv = tid >> 6;
    const int bid = (blockIdx.x & 7) * 64 + (blockIdx.x >> 3);
    const int b = bid >> 7;
    const int ho = bid & 127;
    const float* __restrict__ xb = x + (size_t)b * C * HW;
    const int p = tid & 127, half = tid >> 7, wo = p;
    const int lrow = lane & 15, lk = lane >> 4;

    f32x4 oacc[2][2];
    #pragma unroll
    for (int mt = 0; mt < 2; ++mt)
        #pragma unroll
        for (int nt = 0; nt < 2; ++nt)
            #pragma unroll
            for (int j = 0; j < 4; ++j) oacc[mt][nt][j] = 0.0f;

    #pragma unroll
    for (int k = 0; k < K2; ++k) {
        const int ky = k / 3, kx = k % 3;
        short8v afrA[2][2];
        #pragma unroll
        for (int ks = 0; ks < 2; ++ks)
            #pragma unroll
            for (int mt = 0; mt < 2; ++mt) {
                const int r = mt * 16 + lrow, cb = ks * 32 + lk * 8;
                #pragma unroll
                for (int j = 0; j < 8; ++j) {
                    float wvv = 0.0f;
                    if (r < 18)      wvv = ow[((size_t)(r * C + cb + j)) * 9 + k];
                    else if (r < 27) wvv = mw[((size_t)((r - 18) * C + cb + j)) * 9 + k];
                    afrA[ks][mt][j] = (short)f2bf(wvv);
                }
            }
        {
            const int y = ho - 1 + ky, xx = wo - 1 + kx;
            const bool v = (y >= 0) & (y < H) & (xx >= 0) & (xx < W);
            const float vf = v ? 1.0f : 0.0f;
            const float* __restrict__ xp = xb + (v ? (y * W + xx) : 0);
            #pragma unroll
            for (int q = 0; q < 4; ++q) {
                unsigned pk[4];
                #pragma unroll
                for (int e = 0; e < 4; ++e) {
                    const int c0 = half * 32 + q * 8 + e * 2;
                    pk[e] = f2bf(vf * xp[(size_t)c0 * HW]) | (f2bf(vf * xp[(size_t)(c0 + 1) * HW]) << 16);
                }
                *(uint4*)(sT + swz(p, half * 64 + q * 16)) = make_uint4(pk[0], pk[1], pk[2], pk[3]);
            }
        }
        __syncthreads();
        #pragma unroll
        for (int ks = 0; ks < 2; ++ks)
            #pragma unroll
            for (int nt = 0; nt < 2; ++nt) {
                const int pc = wv * 32 + nt * 16 + lrow;
                short8v bfr = *(const short8v*)(sT + swz(pc, ks * 64 + lk * 16));
                #pragma unroll
                for (int mt = 0; mt < 2; ++mt)
                    oacc[mt][nt] = __builtin_amdgcn_mfma_f32_16x16x32_bf16(afrA[ks][mt], bfr, oacc[mt][nt], 0, 0, 0);
            }
        __syncthreads();
    }

    #pragma unroll
    for (int mt = 0; mt < 2; ++mt)
        #pragma unroll
        for (int nt = 0; nt < 2; ++nt)
            #pragma unroll
            for (int j = 0; j < 4; ++j) {
                const int r = mt * 16 + lk * 4 + j;
                const int pc = wv * 32 + nt * 16 + lrow;
                float bv = 0.0f;
                if (r < 18)      bv = ob[r];
                else if (r < 27) bv = mb[r - 18];
                offL[r * PIX + pc] = oacc[mt][nt][j] + bv;
            }
    __syncthreads();

    float sy[K2], sx[K2];
    #pragma unroll
    for (int k = 0; k < K2; ++k) {
        sy[k] = (float)ho + offL[k * PIX + p];
        sx[k] = (float)wo + offL[(9 + k) * PIX + p];
    }
    if (half == 0) {
        float mm = 0.0f;
        #pragma unroll
        for (int k = 0; k < K2; ++k)
            mm += 1.0f / (1.0f + __expf(-offL[(18 + k) * PIX + p]));
        mmL[p] = mm * (1.0f / 9.0f);
    }

    f32x4 acc[8];
    #pragma unroll
    for (int nt = 0; nt < 8; ++nt)
        #pragma unroll
        for (int j = 0; j < 4; ++j) acc[nt][j] = 0.0f;

    #pragma unroll
    for (int k = 0; k < K2; ++k) {
        short8v afr[2];
        #pragma unroll
        for (int ks = 0; ks < 2; ++ks) {
            const int o = wv * 16 + lrow, cb = ks * 32 + lk * 8;
            #pragma unroll
            for (int j = 0; j < 8; ++j)
                afr[ks][j] = (short)f2bf(weight[((size_t)(o * C + cb + j)) * 9 + k]);
        }
        {
            const float fy = floorf(sy[k]), fx = floorf(sx[k]);
            const float wy1 = sy[k] - fy, wx1 = sx[k] - fx;
            const float wy0 = 1.0f - wy1, wx0 = 1.0f - wx1;
            const int y0 = (int)fy, x0 = (int)fx, y1 = y0 + 1, x1 = x0 + 1;
            const float vy0 = (y0 >= 0 && y0 < H) ? 1.0f : 0.0f;
            const float vy1 = (y1 >= 0 && y1 < H) ? 1.0f : 0.0f;
            const float vx0 = (x0 >= 0 && x0 < W) ? 1.0f : 0.0f;
            const float vx1 = (x1 >= 0 && x1 < W) ? 1.0f : 0.0f;
            const int cy0 = min(max(y0, 0), H - 1), cy1 = min(max(y1, 0), H - 1);
            const int cx0 = min(max(x0, 0), W - 1), cx1 = min(max(x1, 0), W - 1);
            const int l00 = cy0 * W + cx0, l01 = cy0 * W + cx1;
            const int l10 = cy1 * W + cx0, l11 = cy1 * W + cx1;
            const float w00 = wy0 * wx0 * vy0 * vx0, w01 = wy0 * wx1 * vy0 * vx1;
            const float w10 = wy1 * wx0 * vy1 * vx0, w11 = wy1 * wx1 * vy1 * vx1;
            #pragma unroll
            for (int q = 0; q < 4; ++q) {
                unsigned pk[4];
                #pragma unroll
                for (int e = 0; e < 4; ++e) {
                    const int c0 = half * 32 + q * 8 + e * 2;
                    const float* __restrict__ xc0 = xb + (size_t)c0 * HW;
                    const float* __restrict__ xc1 = xc0 + HW;
                    const float s0 = w00 * xc0[l00] + w01 * xc0[l01] + w10 * xc0[l10] + w11 * xc0[l11];
                    const float s1 = w00 * xc1[l00] + w01 * xc1[l01] + w10 * xc1[l10] + w11 * xc1[l11];
                    pk[e] = f2bf(s0) | (f2bf(s1) << 16);
                }
                *(uint4*)(sT + swz(p, half * 64 + q * 16)) = make_uint4(pk[0], pk[1], pk[2], pk[3]);
            }
        }
        __syncthreads();
        #pragma unroll
        for (int ks = 0; ks < 2; ++ks)
            #pragma unroll
            for (int nt = 0; nt < 8; ++nt) {
                const int pc = nt * 16 + lrow;
                short8v bfr = *(const short8v*)(sT + swz(pc, ks * 64 + lk * 16));
                acc[nt] = __builtin_amdgcn_mfma_f32_16x16x32_bf16(afr[ks], bfr, acc[nt], 0, 0, 0);
            }
        __syncthreads();
    }

    float bv[4];
    #pragma unroll
    for (int j = 0; j < 4; ++j) bv[j] = bias[wv * 16 + lk * 4 + j];
    #pragma unroll
    for (int nt = 0; nt < 8; ++nt) {
        const int pc = nt * 16 + lrow;
        const float mmv = mmL[pc];
        #pragma unroll
        for (int j = 0; j < 4; ++j) {
            const int o = wv * 16 + lk * 4 + j;
            out[((size_t)(b * O + o)) * HW + ho * W + pc] = acc[nt][j] * mmv + bv[j];
        }
    }
}

} // namespace

extern "C" void kernel_launch(void* const* d_in, const int* in_sizes, int n_in,
                              void* d_out, int out_size, void* d_ws, size_t ws_size,
                              hipStream_t stream)
{
    const float* x  = (const float*)d_in[0];
    const float* w  = (const float*)d_in[1];
    const float* bs = (const float*)d_in[2];
    const float* ow = (const float*)d_in[3];
    const float* ob = (const float*)d_in[4];
    const float* mw = (const float*)d_in[5];
    const float* mb = (const float*)d_in[6];
    float* out = (float*)d_out;

    if (ws_size < WS_NEED) {
        dim3 grid(B * H), block(256);
        hipLaunchKernelGGL(dcn_fallback, grid, block, 0, stream,
                           x, w, bs, ow, ob, mw, mb, out);
        return;
    }

    unsigned char* ws = (unsigned char*)d_ws;
    hipLaunchKernelGGL(k0_pack, dim3(27), dim3(256), 0, stream, w, ow, mw, ws);
    hipLaunchKernelGGL(dcn_fused3, dim3(1024), dim3(256), 0, stream,
                       x, bs, ob, mb, (const unsigned char*)ws, out);
}